// Round 1
// baseline (1424.112 us; speedup 1.0000x reference)
//
#include <hip/hip_runtime.h>

#define EPSF 1e-8f

constexpr int NB = 64;   // batch
constexpr int NO = 64;   // out capsules
constexpr int NI = 1152; // in capsules
constexpr int ND = 16;   // pose dims

// Half-e W tile in LDS, row-PAIR layout: rows (2k,2k+1) occupy 1024 contiguous
// bytes (gl_lds16 writes 1 KB linearly: lanes 0-31 -> row 2k, lanes 32-63 ->
// row 2k+1) followed by a 16 B pad. Pair stride 1040 B keeps ds_read_b128
// conflict-free: 16B-granule index = (o>>1)%8 -> 2 lanes/granule per 16-lane
// group (2-way = free, same degree as the measured-0-conflict 260-stride
// full-row layout). Two half-tiles double-buffered: 66,560 B -> 2 blocks/CU.
constexpr int PSTRIDE = 260;           // floats per row-pair (2*128 data + 4 pad)
constexpr int HBUFSZ  = 32 * PSTRIDE;  // one half-tile: 64 rows x 128 floats

typedef float v2f __attribute__((ext_vector_type(2)));

// fp32 row loader ------------------------------------------------------------
__device__ __forceinline__ void loadrow16f(const float* __restrict__ base,
                                           size_t elem, float* f){
  const float4* p = (const float4*)(base + elem);
  float4 x0=p[0], x1=p[1], x2=p[2], x3=p[3];
  f[0]=x0.x; f[1]=x0.y; f[2]=x0.z; f[3]=x0.w;
  f[4]=x1.x; f[5]=x1.y; f[6]=x1.z; f[7]=x1.w;
  f[8]=x2.x; f[9]=x2.y; f[10]=x2.z; f[11]=x2.w;
  f[12]=x3.x; f[13]=x3.y; f[14]=x3.z; f[15]=x3.w;
}

// async global->LDS, 16 B per lane; lds dst is wave-uniform base + lane*16
__device__ __forceinline__ void gl_lds16(const float* g, float* l){
  __builtin_amdgcn_global_load_lds(
      (const __attribute__((address_space(1))) unsigned int*)g,
      (__attribute__((address_space(3))) unsigned int*)l,
      16, 0, 0);
}

// ---------------- heavy kernel --------------------------------------------
// grid 1-D: bid = bg*CH + c (CH%8==0 -> same-c blocks share bid%8 -> same XCD;
// W slice NI/CH cols stays in that XCD's L2). Block = NW waves; wave w owns
// batches b0=bg*2NW+2w, b1=b0+1 packed into float2 lanes (v_pk_fma_f32).
// Per i: W[:,i,:,:] staged in TWO e-halves (32 KB each) into buf0/buf1 so LDS
// stays at 66.5 KB -> 2 blocks/CU co-resident; while one block drains its
// barrier/DMA the other computes. Lane=o reads its row pair-slot via
// ds_read_b128 (conflict-free); V, softmax (wave shuffle over o), moments all
// in registers/packed.
template<int NW, bool ESTEP>
__global__ __launch_bounds__(NW*64, NW/2) void k_heavy(
    const float* __restrict__ u, const float* __restrict__ W,
    const float* __restrict__ bias,
    const float* __restrict__ mean0, const float* __restrict__ i2v0,
    const float* __restrict__ c0,
    float* __restrict__ S1p, float* __restrict__ S2p, float* __restrict__ Wsp,
    const int CH)
{
  const int CI = NI / CH;
  constexpr int ROWS = 64 / NW;
  const int bid = blockIdx.x;
  const int bg = bid / CH, c = bid % CH;
  const int t = threadIdx.x, lane = t & 63, w = t >> 6;
  const int b0 = bg*(2*NW) + 2*w, b1 = b0 + 1;
  const int i0 = c*CI;

  __shared__ float buf[2*HBUFSZ];   // 66,560 B -> 2 blocks/CU

  // per-lane (=o) constants
  float bs[16]; loadrow16f(bias, (size_t)lane*ND, bs);
  v2f mr[16], ir[16]; v2f c01 = {0.f, 0.f};
  if (ESTEP){
    const size_t m0 = ((size_t)b0*NO + lane)*ND;
    const size_t m1 = ((size_t)b1*NO + lane)*ND;
    #pragma unroll
    for (int e=0;e<16;++e){
      mr[e] = v2f{mean0[m0+e], mean0[m1+e]};
      ir[e] = v2f{i2v0[m0+e], i2v0[m1+e]};
    }
    c01 = v2f{c0[(size_t)b0*NO + lane], c0[(size_t)b1*NO + lane]};
  }

  v2f S1[16], S2[16]; v2f wsum = {0.f, 0.f};
  #pragma unroll
  for (int e=0;e<16;++e){ S1[e]=v2f{0.f,0.f}; S2[e]=v2f{0.f,0.f}; }

  // stage e-half h of W column i into half-buffer p.
  // wave w covers rows o = w*ROWS .. w*ROWS+ROWS-1, one gl_lds16 per row pair:
  // lanes 0-31 fetch row o0's 512B half, lanes 32-63 fetch row o0+1's.
  const int hl = lane & 31, rsel = lane >> 5;
  auto stage = [&](int p, int i, int h){
    const float* gb = W + (size_t)i*256 + (size_t)h*128 + (size_t)hl*4;
    float* lb = &buf[p*HBUFSZ + (w*(ROWS/2))*PSTRIDE];
    #pragma unroll
    for (int r=0;r<ROWS/2;++r){
      const int o = w*ROWS + 2*r + rsel;
      gl_lds16(gb + (size_t)o*NI*256, lb + r*PSTRIDE);
    }
  };

  // lane=o read base within a half-buffer (pair layout)
  const float* rowp = &buf[(lane>>1)*PSTRIDE + (lane&1)*128];

  stage(0, i0, 0);                       // buf0 <- (i0, e-half 0)

  for (int ii=0; ii<CI; ++ii){
    const int i = i0 + ii;
    __syncthreads();                     // buf0(i,h0) ready; buf1 reads (i-1) done
    stage(1, i, 1);                      // async: buf1 <- (i, e-half 1)

    // u rows for both batches, interleaved into float2 (broadcast loads)
    v2f u01[16];
    {
      const float4* pa = (const float4*)(u + ((size_t)b0*NI + i)*ND);
      const float4* pb = (const float4*)(u + ((size_t)b1*NI + i)*ND);
      #pragma unroll
      for (int q=0;q<4;++q){
        float4 xa = pa[q], xb = pb[q];
        u01[q*4+0] = v2f{xa.x, xb.x};
        u01[q*4+1] = v2f{xa.y, xb.y};
        u01[q*4+2] = v2f{xa.z, xb.z};
        u01[q*4+3] = v2f{xa.w, xb.w};
      }
    }
    v2f ss = {0.f, 0.f};
    #pragma unroll
    for (int d=0;d<16;++d){ v2f x = u01[d] + EPSF; ss += x*x; }
    const v2f av = {sqrtf(ss.x), sqrtf(ss.y)};

    // V for this lane's o, both batches packed
    v2f V[16];
    #pragma unroll
    for (int e=0;e<16;++e){ float b = bs[e] + EPSF; V[e] = v2f{b, b}; }
    // e-half 0 (e = 0..7) from buf0
    #pragma unroll
    for (int e=0;e<8;++e){
      #pragma unroll
      for (int dq=0; dq<4; ++dq){
        const float4 wv = *(const float4*)(rowp + e*16 + dq*4);
        const int d = dq*4;
        V[e] += wv.x*u01[d+0];
        V[e] += wv.y*u01[d+1];
        V[e] += wv.z*u01[d+2];
        V[e] += wv.w*u01[d+3];
      }
    }
    __syncthreads();                     // buf1(i,h1) ready; buf0 reads done
    if (ii+1 < CI) stage(0, i+1, 0);     // async: buf0 <- (i+1, e-half 0)
    // e-half 1 (e = 8..15) from buf1
    #pragma unroll
    for (int e=0;e<8;++e){
      #pragma unroll
      for (int dq=0; dq<4; ++dq){
        const float4 wv = *(const float4*)(rowp + HBUFSZ + e*16 + dq*4);
        const int d = dq*4;
        V[8+e] += wv.x*u01[d+0];
        V[8+e] += wv.y*u01[d+1];
        V[8+e] += wv.z*u01[d+2];
        V[8+e] += wv.w*u01[d+3];
      }
    }

    v2f wg;
    if (ESTEP){
      v2f la = {0.f, 0.f};
      #pragma unroll
      for (int e=0;e<16;++e){ v2f df = V[e]-mr[e]; la += df*df*ir[e]; }
      v2f ap = c01 * v2f{__expf(-la.x), __expf(-la.y)};
      float q0 = ap.x, q1 = ap.y;
      #pragma unroll
      for (int off=32; off; off>>=1){
        q0 += __shfl_xor(q0, off);
        q1 += __shfl_xor(q1, off);
      }
      wg = v2f{ap.x/(q0 + EPSF)*av.x, ap.y/(q1 + EPSF)*av.y};
    } else {
      wg = av;                      // uniform rr: 1/64 applied in k_mred
    }
    wsum += wg;
    #pragma unroll
    for (int e=0;e<16;++e){
      v2f tv = wg*V[e]; S1[e]+=tv; S2[e]+=tv*V[e];
    }
  }

  // store partials: each wave owns distinct b -> no cross-wave reduction
  const size_t ba = (((size_t)b0*CH + c)*NO + lane);
  const size_t bb = (((size_t)b1*CH + c)*NO + lane);
  #pragma unroll
  for (int e=0;e<16;++e){
    S1p[ba*ND+e]=S1[e].x; S2p[ba*ND+e]=S2[e].x;
    S1p[bb*ND+e]=S1[e].y; S2p[bb*ND+e]=S2[e].y;
  }
  Wsp[ba] = wsum.x; Wsp[bb] = wsum.y;  // m-pass: sum a_i; e-pass: sum rr*a
}

// ---------------- reduce m-step partials -> mean0,i2v0,c0 -------------------
// all 64 lanes work: lanes 0-31 sum S1 (e=t&15, c-parity t>>4), lanes 32-63
// sum S2; parities combined via shfl_xor(16); Wsp summed wave-wide.
__global__ __launch_bounds__(64) void k_mred(
    const float* __restrict__ beta_a, const float* __restrict__ beta_u,
    const float* __restrict__ S1p, const float* __restrict__ S2p,
    const float* __restrict__ Wsp, const int CH,
    float* __restrict__ mean0, float* __restrict__ i2v0, float* __restrict__ c0)
{
  const int bo = blockIdx.x;
  const int b = bo >> 6, o = bo & 63;
  const int t = threadIdx.x;
  const int e = t & 15, g = (t >> 4) & 1;
  const float* __restrict__ P = (t >= 32) ? S2p : S1p;
  float s = 0.f;
  for (int c = g; c < CH; c += 2)
    s += P[((((size_t)b*CH)+c)*NO + o)*ND + e];
  s += __shfl_xor(s, 16);
  float wv = 0.f;
  for (int c = t; c < CH; c += 64)
    wv += Wsp[(((size_t)b*CH)+c)*NO + o];
  #pragma unroll
  for (int off = 32; off; off >>= 1) wv += __shfl_xor(wv, off);

  __shared__ float S1s[16], S2s[16];
  __shared__ float ct_s[16], vt_s[16];
  if (t < 16) S1s[e] = s;
  else if (t >= 32 && t < 48) S2s[e] = s;
  __syncthreads();
  const float rrsum = wv * (1.f/64.f);
  if (t < 16){
    float T1 = S1s[t]*(1.f/64.f);
    float T2 = S2s[t]*(1.f/64.f);
    float m  = T1/(rrsum + EPSF);
    float var = (T2 - 2.f*m*T1 + m*m*rrsum)/(rrsum + EPSF) + 1e-4f;
    const size_t mbase = ((size_t)b*NO + o)*ND;
    mean0[mbase+t] = m;
    i2v0[mbase+t]  = 1.f/(2.f*var + EPSF);
    ct_s[t] = beta_u[o] + __logf(var);
    vt_s[t] = var;
  }
  __syncthreads();
  if (t == 0){
    float cost = 0.f, prod = 1.f;
    #pragma unroll
    for (int e2=0;e2<16;++e2){ cost += ct_s[e2]; prod *= vt_s[e2]; }
    cost *= rrsum;
    float x  = 5.0e-4f*(beta_a[o] - cost);   // inv_temp iter0 = 0.01*(1-0.95)
    float aj = 1.f/(1.f + __expf(-x));
    float p1 = sqrtf(6.2831853071795864f*prod + EPSF);
    c0[(size_t)b*NO + o] = aj/(p1 + EPSF);
  }
}

// ---------------- final: reduce e-partials, write output (fp32) -------------
__global__ __launch_bounds__(64) void k_final(
    const float* __restrict__ beta_a, const float* __restrict__ beta_u,
    const float* __restrict__ S1p, const float* __restrict__ S2p,
    const float* __restrict__ Wsp, const int CH,
    float* __restrict__ out)
{
  const int bo = blockIdx.x;
  const int b = bo >> 6, o = bo & 63;
  const int t = threadIdx.x;
  const int e = t & 15, g = (t >> 4) & 1;
  const float* __restrict__ P = (t >= 32) ? S2p : S1p;
  float s = 0.f;
  for (int c = g; c < CH; c += 2)
    s += P[((((size_t)b*CH)+c)*NO + o)*ND + e];
  s += __shfl_xor(s, 16);
  float wv = 0.f;
  for (int c = t; c < CH; c += 64)
    wv += Wsp[(((size_t)b*CH)+c)*NO + o];
  #pragma unroll
  for (int off = 32; off; off >>= 1) wv += __shfl_xor(wv, off);

  __shared__ float S1s[16], S2s[16];
  __shared__ float mean_s[16], ct_s[16], nt_s[16];
  __shared__ float scale_s;
  if (t < 16) S1s[e] = s;
  else if (t >= 32 && t < 48) S2s[e] = s;
  __syncthreads();
  const float Wsum = wv;
  if (t < 16){
    float S1 = S1s[t], S2 = S2s[t];
    float m = S1/(Wsum + EPSF);
    float var = (S2 - 2.f*m*S1 + m*m*Wsum)/(Wsum + EPSF) + 1e-4f;
    mean_s[t] = m;
    ct_s[t] = beta_u[o] + __logf(var);
    float me = m + EPSF;
    nt_s[t] = me*me;
  }
  __syncthreads();
  if (t == 0){
    float cost=0.f, nrm=0.f;
    #pragma unroll
    for (int e2=0;e2<16;++e2){ cost += ct_s[e2]; nrm += nt_s[e2]; }
    cost *= Wsum;
    float x = 9.75e-4f*(beta_a[o] - cost);  // inv_temp iter1 = 0.01*(1-0.95^2)
    float aj = 1.f/(1.f + __expf(-x));
    scale_s = aj/(sqrtf(nrm) + EPSF);
  }
  __syncthreads();
  if (t < 16){
    out[(size_t)bo*ND + t] = scale_s*mean_s[t];   // fp32 store
  }
}

// ---------------- host ------------------------------------------------------
extern "C" void kernel_launch(void* const* d_in, const int* in_sizes, int n_in,
                              void* d_out, int out_size, void* d_ws, size_t ws_size,
                              hipStream_t stream)
{
  const float* u      = (const float*)d_in[0];
  const float* W      = (const float*)d_in[1];
  const float* beta_a = (const float*)d_in[2];
  const float* beta_u = (const float*)d_in[3];
  const float* bias   = (const float*)d_in[4];
  float* ws  = (float*)d_ws;
  float* out = (float*)d_out;

  const size_t base_f = 2u*NB*NO*ND + NB*NO;                  // 135,168 floats
  auto need = [&](int ch){
    return (base_f + 2u*(size_t)NB*ch*NO*ND + (size_t)NB*ch*NO)*4;
  };
  // CH=128 -> grid 512 -> 2 blocks/CU (66.5 KB LDS each). Fallbacks keep
  // correctness at smaller workspace sizes.
  int CH, mode;
  if (ws_size >= need(128))      { CH = 128; mode = 2; }
  else if (ws_size >= need(64))  { CH = 64;  mode = 1; }
  else                           { CH = 32;  mode = 0; }

  float* mean0= ws;
  float* i2v0 = mean0 + (size_t)NB*NO*ND;
  float* c0   = i2v0 + (size_t)NB*NO*ND;
  float* S1p  = c0   + (size_t)NB*NO;
  float* S2p  = S1p  + (size_t)NB*CH*NO*ND;
  float* Wsp  = S2p  + (size_t)NB*CH*NO*ND;

  if (mode >= 1){
    const int GRID = (NB/16)*CH;   // mode2: 512 blocks -> 2/CU; mode1: 256
    k_heavy<8,false><<<GRID, 512, 0, stream>>>(u, W, bias,
                                               nullptr, nullptr, nullptr,
                                               S1p, S2p, Wsp, CH);
    k_mred<<<NB*NO, 64, 0, stream>>>(beta_a, beta_u, S1p, S2p, Wsp, CH,
                                     mean0, i2v0, c0);
    k_heavy<8,true><<<GRID, 512, 0, stream>>>(u, W, bias,
                                              mean0, i2v0, c0,
                                              S1p, S2p, Wsp, CH);
  } else {
    const int GRID = (NB/8)*CH;    // 256 blocks of 4 waves
    k_heavy<4,false><<<GRID, 256, 0, stream>>>(u, W, bias,
                                               nullptr, nullptr, nullptr,
                                               S1p, S2p, Wsp, CH);
    k_mred<<<NB*NO, 64, 0, stream>>>(beta_a, beta_u, S1p, S2p, Wsp, CH,
                                     mean0, i2v0, c0);
    k_heavy<4,true><<<GRID, 256, 0, stream>>>(u, W, bias,
                                              mean0, i2v0, c0,
                                              S1p, S2p, Wsp, CH);
  }
  k_final<<<NB*NO, 64, 0, stream>>>(beta_a, beta_u, S1p, S2p, Wsp, CH, out);
}

// Round 2
// 606.172 us; speedup vs baseline: 2.3494x; 2.3494x over previous
//
#include <hip/hip_runtime.h>

#define EPSF 1e-8f

constexpr int NB = 64;   // batch
constexpr int NO = 64;   // out capsules
constexpr int NI = 1152; // in capsules
constexpr int ND = 16;   // pose dims

// Half-e W tile in LDS, row-PAIR layout: rows (2k,2k+1) occupy 1024 contiguous
// bytes (gl_lds16 writes 1 KB linearly: lanes 0-31 -> row 2k's 512B half,
// lanes 32-63 -> row 2k+1's) followed by a 16 B pad -> pair stride 1040 B.
// READ side: lane->row remap (lanes 0-31 = even rows, 32-63 = odd rows) makes
// per-8-lane-beat 16B granules ((lane&31)+c mod 8) distinct -> conflict-free
// (granule-beat model fits: 1040B full-row stride measured 0 conflicts, naive
// pair read measured 9.4M). Two half-tiles double-buffered: 66,560 B ->
// 2 blocks/CU co-resident (the R1 counters' occupancy win, minus the spill).
constexpr int PSTRIDE = 260;           // floats per row-pair (2*128 data + 4 pad)
constexpr int HBUFSZ  = 32 * PSTRIDE;  // one half-tile: 64 rows x 128 floats

typedef float v2f __attribute__((ext_vector_type(2)));

// fp32 row loader ------------------------------------------------------------
__device__ __forceinline__ void loadrow16f(const float* __restrict__ base,
                                           size_t elem, float* f){
  const float4* p = (const float4*)(base + elem);
  float4 x0=p[0], x1=p[1], x2=p[2], x3=p[3];
  f[0]=x0.x; f[1]=x0.y; f[2]=x0.z; f[3]=x0.w;
  f[4]=x1.x; f[5]=x1.y; f[6]=x1.z; f[7]=x1.w;
  f[8]=x2.x; f[9]=x2.y; f[10]=x2.z; f[11]=x2.w;
  f[12]=x3.x; f[13]=x3.y; f[14]=x3.z; f[15]=x3.w;
}

// async global->LDS, 16 B per lane; lds dst is wave-uniform base + lane*16
__device__ __forceinline__ void gl_lds16(const float* g, float* l){
  __builtin_amdgcn_global_load_lds(
      (const __attribute__((address_space(1))) unsigned int*)g,
      (__attribute__((address_space(3))) unsigned int*)l,
      16, 0, 0);
}

// ---------------- heavy kernel --------------------------------------------
// grid 1-D: bid = bg*CH + c (CH%8==0 -> same-c blocks share bid%8 -> same XCD;
// W slice NI/CH cols stays in that XCD's L2). Block = NW waves; wave w owns
// batches b0=bg*2NW+2w, b1=b0+1 packed into float2 lanes (v_pk_fma_f32).
// Per i: W[:,i,:,:] staged in TWO e-halves (32.5 KB each) into buf0/buf1 so
// LDS stays at 66.5 KB -> 2 blocks/CU; V, softmax (wave shuffle over o),
// moments all in registers/packed.
// NOTE launch_bounds 2nd arg: measured on this toolchain it acts like CUDA
// min-blocks/CU ((512,2)->128 VGPR, (512,4)->64 VGPR+spill). Keep 2.
template<int NW, bool ESTEP>
__global__ __launch_bounds__(NW*64, 2) void k_heavy(
    const float* __restrict__ u, const float* __restrict__ W,
    const float* __restrict__ bias,
    const float* __restrict__ mean0, const float* __restrict__ i2v0,
    const float* __restrict__ c0,
    float* __restrict__ S1p, float* __restrict__ S2p, float* __restrict__ Wsp,
    const int CH)
{
  const int CI = NI / CH;
  constexpr int ROWS = 64 / NW;
  const int bid = blockIdx.x;
  const int bg = bid / CH, c = bid % CH;
  const int t = threadIdx.x, lane = t & 63, w = t >> 6;
  const int b0 = bg*(2*NW) + 2*w, b1 = b0 + 1;
  const int i0 = c*CI;

  // lane -> output-capsule row remap (conflict-free pair-layout reads):
  // lanes 0-31 own even rows, lanes 32-63 own odd rows.
  const int ro = ((lane & 31) << 1) | (lane >> 5);

  __shared__ float buf[2*HBUFSZ];   // 66,560 B -> 2 blocks/CU

  // per-lane (=ro) constants
  float bs[16]; loadrow16f(bias, (size_t)ro*ND, bs);
  v2f mr[16], ir[16]; v2f c01 = {0.f, 0.f};
  if (ESTEP){
    const size_t m0 = ((size_t)b0*NO + ro)*ND;
    const size_t m1 = ((size_t)b1*NO + ro)*ND;
    #pragma unroll
    for (int e=0;e<16;++e){
      mr[e] = v2f{mean0[m0+e], mean0[m1+e]};
      ir[e] = v2f{i2v0[m0+e], i2v0[m1+e]};
    }
    c01 = v2f{c0[(size_t)b0*NO + ro], c0[(size_t)b1*NO + ro]};
  }

  v2f S1[16], S2[16]; v2f wsum = {0.f, 0.f};
  #pragma unroll
  for (int e=0;e<16;++e){ S1[e]=v2f{0.f,0.f}; S2[e]=v2f{0.f,0.f}; }

  // stage e-half h of W column i into half-buffer p.
  // wave w covers rows o = w*ROWS .. w*ROWS+ROWS-1, one gl_lds16 per row pair:
  // lanes 0-31 fetch row o0's 512B half, lanes 32-63 fetch row o0+1's.
  const int hl = lane & 31, rsel = lane >> 5;
  auto stage = [&](int p, int i, int h){
    const float* gb = W + (size_t)i*256 + (size_t)h*128 + (size_t)hl*4;
    float* lb = &buf[p*HBUFSZ + (w*(ROWS/2))*PSTRIDE];
    #pragma unroll
    for (int r=0;r<ROWS/2;++r){
      const int o = w*ROWS + 2*r + rsel;
      gl_lds16(gb + (size_t)o*NI*256, lb + r*PSTRIDE);
    }
  };

  // lane read base within a half-buffer (pair layout, remapped):
  // row ro lives at (ro>>1)*PSTRIDE + (ro&1)*128 = (lane&31)*PSTRIDE + (lane>>5)*128
  const float* rowp = &buf[(lane & 31)*PSTRIDE + (lane >> 5)*128];

  stage(0, i0, 0);                       // buf0 <- (i0, e-half 0)

  for (int ii=0; ii<CI; ++ii){
    const int i = i0 + ii;
    __syncthreads();                     // buf0(i,h0) ready; buf1 reads (i-1) done
    stage(1, i, 1);                      // async: buf1 <- (i, e-half 1)

    // u rows for both batches, interleaved into float2 (broadcast loads)
    v2f u01[16];
    {
      const float4* pa = (const float4*)(u + ((size_t)b0*NI + i)*ND);
      const float4* pb = (const float4*)(u + ((size_t)b1*NI + i)*ND);
      #pragma unroll
      for (int q=0;q<4;++q){
        float4 xa = pa[q], xb = pb[q];
        u01[q*4+0] = v2f{xa.x, xb.x};
        u01[q*4+1] = v2f{xa.y, xb.y};
        u01[q*4+2] = v2f{xa.z, xb.z};
        u01[q*4+3] = v2f{xa.w, xb.w};
      }
    }
    v2f ss = {0.f, 0.f};
    #pragma unroll
    for (int d=0;d<16;++d){ v2f x = u01[d] + EPSF; ss += x*x; }
    const v2f av = {sqrtf(ss.x), sqrtf(ss.y)};

    // V for this lane's ro, both batches packed
    v2f V[16];
    #pragma unroll
    for (int e=0;e<16;++e){ float b = bs[e] + EPSF; V[e] = v2f{b, b}; }
    // e-half 0 (e = 0..7) from buf0
    #pragma unroll
    for (int e=0;e<8;++e){
      #pragma unroll
      for (int dq=0; dq<4; ++dq){
        const float4 wv = *(const float4*)(rowp + e*16 + dq*4);
        const int d = dq*4;
        V[e] += wv.x*u01[d+0];
        V[e] += wv.y*u01[d+1];
        V[e] += wv.z*u01[d+2];
        V[e] += wv.w*u01[d+3];
      }
    }
    __syncthreads();                     // buf1(i,h1) ready; buf0 reads done
    if (ii+1 < CI) stage(0, i+1, 0);     // async: buf0 <- (i+1, e-half 0)
    // e-half 1 (e = 8..15) from buf1
    #pragma unroll
    for (int e=0;e<8;++e){
      #pragma unroll
      for (int dq=0; dq<4; ++dq){
        const float4 wv = *(const float4*)(rowp + HBUFSZ + e*16 + dq*4);
        const int d = dq*4;
        V[8+e] += wv.x*u01[d+0];
        V[8+e] += wv.y*u01[d+1];
        V[8+e] += wv.z*u01[d+2];
        V[8+e] += wv.w*u01[d+3];
      }
    }

    v2f wg;
    if (ESTEP){
      v2f la = {0.f, 0.f};
      #pragma unroll
      for (int e=0;e<16;++e){ v2f df = V[e]-mr[e]; la += df*df*ir[e]; }
      v2f ap = c01 * v2f{__expf(-la.x), __expf(-la.y)};
      float q0 = ap.x, q1 = ap.y;
      #pragma unroll
      for (int off=32; off; off>>=1){
        q0 += __shfl_xor(q0, off);
        q1 += __shfl_xor(q1, off);
      }
      wg = v2f{ap.x/(q0 + EPSF)*av.x, ap.y/(q1 + EPSF)*av.y};
    } else {
      wg = av;                      // uniform rr: 1/64 applied in k_mred
    }
    wsum += wg;
    #pragma unroll
    for (int e=0;e<16;++e){
      v2f tv = wg*V[e]; S1[e]+=tv; S2[e]+=tv*V[e];
    }
  }

  // store partials: each wave owns distinct b -> no cross-wave reduction
  const size_t ba = (((size_t)b0*CH + c)*NO + ro);
  const size_t bb = (((size_t)b1*CH + c)*NO + ro);
  #pragma unroll
  for (int e=0;e<16;++e){
    S1p[ba*ND+e]=S1[e].x; S2p[ba*ND+e]=S2[e].x;
    S1p[bb*ND+e]=S1[e].y; S2p[bb*ND+e]=S2[e].y;
  }
  Wsp[ba] = wsum.x; Wsp[bb] = wsum.y;  // m-pass: sum a_i; e-pass: sum rr*a
}

// ---------------- reduce m-step partials -> mean0,i2v0,c0 -------------------
// all 64 lanes work: lanes 0-31 sum S1 (e=t&15, c-parity t>>4), lanes 32-63
// sum S2; parities combined via shfl_xor(16); Wsp summed wave-wide.
__global__ __launch_bounds__(64) void k_mred(
    const float* __restrict__ beta_a, const float* __restrict__ beta_u,
    const float* __restrict__ S1p, const float* __restrict__ S2p,
    const float* __restrict__ Wsp, const int CH,
    float* __restrict__ mean0, float* __restrict__ i2v0, float* __restrict__ c0)
{
  const int bo = blockIdx.x;
  const int b = bo >> 6, o = bo & 63;
  const int t = threadIdx.x;
  const int e = t & 15, g = (t >> 4) & 1;
  const float* __restrict__ P = (t >= 32) ? S2p : S1p;
  float s = 0.f;
  for (int c = g; c < CH; c += 2)
    s += P[((((size_t)b*CH)+c)*NO + o)*ND + e];
  s += __shfl_xor(s, 16);
  float wv = 0.f;
  for (int c = t; c < CH; c += 64)
    wv += Wsp[(((size_t)b*CH)+c)*NO + o];
  #pragma unroll
  for (int off = 32; off; off >>= 1) wv += __shfl_xor(wv, off);

  __shared__ float S1s[16], S2s[16];
  __shared__ float ct_s[16], vt_s[16];
  if (t < 16) S1s[e] = s;
  else if (t >= 32 && t < 48) S2s[e] = s;
  __syncthreads();
  const float rrsum = wv * (1.f/64.f);
  if (t < 16){
    float T1 = S1s[t]*(1.f/64.f);
    float T2 = S2s[t]*(1.f/64.f);
    float m  = T1/(rrsum + EPSF);
    float var = (T2 - 2.f*m*T1 + m*m*rrsum)/(rrsum + EPSF) + 1e-4f;
    const size_t mbase = ((size_t)b*NO + o)*ND;
    mean0[mbase+t] = m;
    i2v0[mbase+t]  = 1.f/(2.f*var + EPSF);
    ct_s[t] = beta_u[o] + __logf(var);
    vt_s[t] = var;
  }
  __syncthreads();
  if (t == 0){
    float cost = 0.f, prod = 1.f;
    #pragma unroll
    for (int e2=0;e2<16;++e2){ cost += ct_s[e2]; prod *= vt_s[e2]; }
    cost *= rrsum;
    float x  = 5.0e-4f*(beta_a[o] - cost);   // inv_temp iter0 = 0.01*(1-0.95)
    float aj = 1.f/(1.f + __expf(-x));
    float p1 = sqrtf(6.2831853071795864f*prod + EPSF);
    c0[(size_t)b*NO + o] = aj/(p1 + EPSF);
  }
}

// ---------------- final: reduce e-partials, write output (fp32) -------------
__global__ __launch_bounds__(64) void k_final(
    const float* __restrict__ beta_a, const float* __restrict__ beta_u,
    const float* __restrict__ S1p, const float* __restrict__ S2p,
    const float* __restrict__ Wsp, const int CH,
    float* __restrict__ out)
{
  const int bo = blockIdx.x;
  const int b = bo >> 6, o = bo & 63;
  const int t = threadIdx.x;
  const int e = t & 15, g = (t >> 4) & 1;
  const float* __restrict__ P = (t >= 32) ? S2p : S1p;
  float s = 0.f;
  for (int c = g; c < CH; c += 2)
    s += P[((((size_t)b*CH)+c)*NO + o)*ND + e];
  s += __shfl_xor(s, 16);
  float wv = 0.f;
  for (int c = t; c < CH; c += 64)
    wv += Wsp[(((size_t)b*CH)+c)*NO + o];
  #pragma unroll
  for (int off = 32; off; off >>= 1) wv += __shfl_xor(wv, off);

  __shared__ float S1s[16], S2s[16];
  __shared__ float mean_s[16], ct_s[16], nt_s[16];
  __shared__ float scale_s;
  if (t < 16) S1s[e] = s;
  else if (t >= 32 && t < 48) S2s[e] = s;
  __syncthreads();
  const float Wsum = wv;
  if (t < 16){
    float S1 = S1s[t], S2 = S2s[t];
    float m = S1/(Wsum + EPSF);
    float var = (S2 - 2.f*m*S1 + m*m*Wsum)/(Wsum + EPSF) + 1e-4f;
    mean_s[t] = m;
    ct_s[t] = beta_u[o] + __logf(var);
    float me = m + EPSF;
    nt_s[t] = me*me;
  }
  __syncthreads();
  if (t == 0){
    float cost=0.f, nrm=0.f;
    #pragma unroll
    for (int e2=0;e2<16;++e2){ cost += ct_s[e2]; nrm += nt_s[e2]; }
    cost *= Wsum;
    float x = 9.75e-4f*(beta_a[o] - cost);  // inv_temp iter1 = 0.01*(1-0.95^2)
    float aj = 1.f/(1.f + __expf(-x));
    scale_s = aj/(sqrtf(nrm) + EPSF);
  }
  __syncthreads();
  if (t < 16){
    out[(size_t)bo*ND + t] = scale_s*mean_s[t];   // fp32 store
  }
}

// ---------------- host ------------------------------------------------------
extern "C" void kernel_launch(void* const* d_in, const int* in_sizes, int n_in,
                              void* d_out, int out_size, void* d_ws, size_t ws_size,
                              hipStream_t stream)
{
  const float* u      = (const float*)d_in[0];
  const float* W      = (const float*)d_in[1];
  const float* beta_a = (const float*)d_in[2];
  const float* beta_u = (const float*)d_in[3];
  const float* bias   = (const float*)d_in[4];
  float* ws  = (float*)d_ws;
  float* out = (float*)d_out;

  const size_t base_f = 2u*NB*NO*ND + NB*NO;                  // 135,168 floats
  auto need = [&](int ch){
    return (base_f + 2u*(size_t)NB*ch*NO*ND + (size_t)NB*ch*NO)*4;
  };
  // CH=128 -> grid 512 -> 2 blocks/CU (66.5 KB LDS each). Fallbacks keep
  // correctness at smaller workspace sizes.
  int CH, mode;
  if (ws_size >= need(128))      { CH = 128; mode = 2; }
  else if (ws_size >= need(64))  { CH = 64;  mode = 1; }
  else                           { CH = 32;  mode = 0; }

  float* mean0= ws;
  float* i2v0 = mean0 + (size_t)NB*NO*ND;
  float* c0   = i2v0 + (size_t)NB*NO*ND;
  float* S1p  = c0   + (size_t)NB*NO;
  float* S2p  = S1p  + (size_t)NB*CH*NO*ND;
  float* Wsp  = S2p  + (size_t)NB*CH*NO*ND;

  if (mode >= 1){
    const int GRID = (NB/16)*CH;   // mode2: 512 blocks -> 2/CU; mode1: 256
    k_heavy<8,false><<<GRID, 512, 0, stream>>>(u, W, bias,
                                               nullptr, nullptr, nullptr,
                                               S1p, S2p, Wsp, CH);
    k_mred<<<NB*NO, 64, 0, stream>>>(beta_a, beta_u, S1p, S2p, Wsp, CH,
                                     mean0, i2v0, c0);
    k_heavy<8,true><<<GRID, 512, 0, stream>>>(u, W, bias,
                                              mean0, i2v0, c0,
                                              S1p, S2p, Wsp, CH);
  } else {
    const int GRID = (NB/8)*CH;    // 256 blocks of 4 waves
    k_heavy<4,false><<<GRID, 256, 0, stream>>>(u, W, bias,
                                               nullptr, nullptr, nullptr,
                                               S1p, S2p, Wsp, CH);
    k_mred<<<NB*NO, 64, 0, stream>>>(beta_a, beta_u, S1p, S2p, Wsp, CH,
                                     mean0, i2v0, c0);
    k_heavy<4,true><<<GRID, 256, 0, stream>>>(u, W, bias,
                                              mean0, i2v0, c0,
                                              S1p, S2p, Wsp, CH);
  }
  k_final<<<NB*NO, 64, 0, stream>>>(beta_a, beta_u, S1p, S2p, Wsp, CH, out);
}

// Round 5
// 331.149 us; speedup vs baseline: 4.3005x; 1.8305x over previous
//
#include <hip/hip_runtime.h>

#define EPSF 1e-8f

constexpr int NB = 64;   // batch
constexpr int NO = 64;   // out capsules
constexpr int NI = 1152; // in capsules
constexpr int ND = 16;   // pose dims

constexpr int RSTRIDE = 260;            // 256 floats + 4 pad (16B-aligned rows)
constexpr int BUFSZ   = 64 * RSTRIDE;   // one W-tile: 64 o-rows (66,560 B)

typedef float v2f __attribute__((ext_vector_type(2)));
typedef float v4f __attribute__((ext_vector_type(4)));

// fp32 row loader ------------------------------------------------------------
__device__ __forceinline__ void loadrow16f(const float* __restrict__ base,
                                           size_t elem, float* f){
  const float4* p = (const float4*)(base + elem);
  float4 x0=p[0], x1=p[1], x2=p[2], x3=p[3];
  f[0]=x0.x; f[1]=x0.y; f[2]=x0.z; f[3]=x0.w;
  f[4]=x1.x; f[5]=x1.y; f[6]=x1.z; f[7]=x1.w;
  f[8]=x2.x; f[9]=x2.y; f[10]=x2.z; f[11]=x2.w;
  f[12]=x3.x; f[13]=x3.y; f[14]=x3.z; f[15]=x3.w;
}

// async global->LDS, 16 B per lane; lds dst is wave-uniform base + lane*16
__device__ __forceinline__ void gl_lds16(const float* g, float* l){
  __builtin_amdgcn_global_load_lds(
      (const __attribute__((address_space(1))) unsigned int*)g,
      (__attribute__((address_space(3))) unsigned int*)l,
      16, 0, 0);
}

// ---------------- heavy kernel (R0-proven shape, unchanged) ----------------
// grid 1-D: bid = bg*CH + c (CH%8==0 -> same-c blocks share bid%8 -> same XCD;
// W slice NI/CH cols stays in that XCD's L2). Block = NW waves; wave w owns
// batches b0=bg*2NW+2w, b1=b0+1 packed into float2 lanes (v_pk_fma_f32).
// Per i: W[:,i,:,:] (64KB) DMA'd to LDS rows [o][256] stride 260 (double-buf);
// lane=o reads its row via ds_read_b128 (conflict-free); V, softmax (wave
// shuffle over o), moments all in registers/packed.
// __launch_bounds__ 2nd arg: measured (512,2)->128 VGPR no-spill; (512,4)
// caps 64 VGPR and spills catastrophically (R1). Keep 2. 1024-thr variant
// (NW=16) failed to launch twice (R3/R4) -- do not reintroduce.
template<int NW, bool ESTEP>
__global__ __launch_bounds__(NW*64, 2) void k_heavy(
    const float* __restrict__ u, const float* __restrict__ W,
    const float* __restrict__ bias,
    const float* __restrict__ mean0, const float* __restrict__ i2v0,
    const float* __restrict__ c0,
    float* __restrict__ S1p, float* __restrict__ S2p, float* __restrict__ Wsp,
    const int CH)
{
  const int CI = NI / CH;
  constexpr int ROWS = 64 / NW;
  const int bid = blockIdx.x;
  const int bg = bid / CH, c = bid % CH;
  const int t = threadIdx.x, lane = t & 63, w = t >> 6;
  const int b0 = bg*(2*NW) + 2*w, b1 = b0 + 1;
  const int i0 = c*CI;

  __shared__ float buf[2*BUFSZ];   // 133,120 B

  // per-lane (=o) constants
  float bs[16]; loadrow16f(bias, (size_t)lane*ND, bs);
  v2f mr[16], ir[16]; v2f c01 = {0.f, 0.f};
  if (ESTEP){
    const size_t m0 = ((size_t)b0*NO + lane)*ND;
    const size_t m1 = ((size_t)b1*NO + lane)*ND;
    #pragma unroll
    for (int e=0;e<16;++e){
      mr[e] = v2f{mean0[m0+e], mean0[m1+e]};
      ir[e] = v2f{i2v0[m0+e], i2v0[m1+e]};
    }
    c01 = v2f{c0[(size_t)b0*NO + lane], c0[(size_t)b1*NO + lane]};
  }

  v2f S1[16], S2[16]; v2f wsum = {0.f, 0.f};
  #pragma unroll
  for (int e=0;e<16;++e){ S1[e]=v2f{0.f,0.f}; S2[e]=v2f{0.f,0.f}; }

  // stage W tile for column i into buffer p: wave w covers ROWS o-rows,
  // one gl_lds16 per row (64 lanes x 16 B = full 1 KB row, linear dst)
  auto stage = [&](int p, int i){
    const float* gbase = W + (size_t)i*256 + (size_t)lane*4;
    float* lbase = &buf[p*BUFSZ];
    #pragma unroll
    for (int r=0;r<ROWS;++r){
      const int o = w*ROWS + r;
      gl_lds16(gbase + (size_t)o*NI*256, lbase + o*RSTRIDE);
    }
  };

  int p = 0;
  stage(0, i0);

  for (int ii=0; ii<CI; ++ii){
    __syncthreads();                      // drains tile-p loads; buffer reuse
    if (ii+1 < CI) stage(p^1, i0+ii+1);   // async, overlaps compute below

    const int i = i0 + ii;
    // u rows for both batches, interleaved into float2 (broadcast loads)
    v2f u01[16];
    {
      const float4* pa = (const float4*)(u + ((size_t)b0*NI + i)*ND);
      const float4* pb = (const float4*)(u + ((size_t)b1*NI + i)*ND);
      #pragma unroll
      for (int q=0;q<4;++q){
        float4 xa = pa[q], xb = pb[q];
        u01[q*4+0] = v2f{xa.x, xb.x};
        u01[q*4+1] = v2f{xa.y, xb.y};
        u01[q*4+2] = v2f{xa.z, xb.z};
        u01[q*4+3] = v2f{xa.w, xb.w};
      }
    }
    v2f ss = {0.f, 0.f};
    #pragma unroll
    for (int d=0;d<16;++d){ v2f x = u01[d] + EPSF; ss += x*x; }
    const v2f av = {sqrtf(ss.x), sqrtf(ss.y)};

    // V for this lane's o, both batches packed (wide LDS reads)
    v2f V[16];
    #pragma unroll
    for (int e=0;e<16;++e){ float b = bs[e] + EPSF; V[e] = v2f{b, b}; }
    const float* row = &buf[p*BUFSZ + lane*RSTRIDE];
    #pragma unroll
    for (int e=0;e<16;++e){
      #pragma unroll
      for (int dq=0; dq<4; ++dq){
        const float4 wv = *(const float4*)(row + e*16 + dq*4);
        const int d = dq*4;
        V[e] += wv.x*u01[d+0];
        V[e] += wv.y*u01[d+1];
        V[e] += wv.z*u01[d+2];
        V[e] += wv.w*u01[d+3];
      }
    }

    v2f wg;
    if (ESTEP){
      v2f la = {0.f, 0.f};
      #pragma unroll
      for (int e=0;e<16;++e){ v2f df = V[e]-mr[e]; la += df*df*ir[e]; }
      v2f ap = c01 * v2f{__expf(-la.x), __expf(-la.y)};
      float q0 = ap.x, q1 = ap.y;
      #pragma unroll
      for (int off=32; off; off>>=1){
        q0 += __shfl_xor(q0, off);
        q1 += __shfl_xor(q1, off);
      }
      wg = v2f{ap.x/(q0 + EPSF)*av.x, ap.y/(q1 + EPSF)*av.y};
    } else {
      wg = av;                      // uniform rr: 1/64 applied in k_mred
    }
    wsum += wg;
    #pragma unroll
    for (int e=0;e<16;++e){
      v2f tv = wg*V[e]; S1[e]+=tv; S2[e]+=tv*V[e];
    }
    p ^= 1;
  }

  // store partials: each wave owns distinct b -> no cross-wave reduction
  const size_t ba = (((size_t)b0*CH + c)*NO + lane);
  const size_t bb = (((size_t)b1*CH + c)*NO + lane);
  #pragma unroll
  for (int e=0;e<16;++e){
    S1p[ba*ND+e]=S1[e].x; S2p[ba*ND+e]=S2[e].x;
    S1p[bb*ND+e]=S1[e].y; S2p[bb*ND+e]=S2[e].y;
  }
  Wsp[ba] = wsum.x; Wsp[bb] = wsum.y;  // m-pass: sum a_i; e-pass: sum rr*a
}

// ---------------- reduce m-step partials -> mean0,i2v0,c0 -------------------
// Wave-parallel v2: all 64 lanes load; lane = (c-group cg = t>>2) x (e-quad
// q = t&3); float4-over-e loads; serial depth CH/16 (=4 at CH=64) instead of
// 32; butterfly shfl_xor combines; epilogue distributed (no t==0 loops).
__global__ __launch_bounds__(64) void k_mred(
    const float* __restrict__ beta_a, const float* __restrict__ beta_u,
    const float* __restrict__ S1p, const float* __restrict__ S2p,
    const float* __restrict__ Wsp, const int CH,
    float* __restrict__ mean0, float* __restrict__ i2v0, float* __restrict__ c0)
{
  const int bo = blockIdx.x;
  const int b = bo >> 6, o = bo & 63;
  const int t = threadIdx.x;
  const int q = t & 3, cg = t >> 2;

  v4f s1 = {0.f,0.f,0.f,0.f}, s2 = {0.f,0.f,0.f,0.f};
  for (int c = cg; c < CH; c += 16){
    const size_t base = ((((size_t)b*CH)+c)*NO + o)*ND + 4*q;
    s1 += *(const v4f*)(S1p + base);
    s2 += *(const v4f*)(S2p + base);
  }
  #pragma unroll
  for (int off=4; off<64; off<<=1){
    #pragma unroll
    for (int k=0;k<4;++k){
      s1[k] += __shfl_xor(s1[k], off);
      s2[k] += __shfl_xor(s2[k], off);
    }
  }
  float wv = 0.f;
  for (int c = t; c < CH; c += 64)
    wv += Wsp[(((size_t)b*CH)+c)*NO + o];
  #pragma unroll
  for (int off=1; off<64; off<<=1) wv += __shfl_xor(wv, off);

  const float rrsum = wv * (1.f/64.f);
  const float inv = 1.f/(rrsum + EPSF);
  const float bu = beta_u[o];
  v4f T1 = s1*(1.f/64.f), T2 = s2*(1.f/64.f);
  v4f m   = T1*inv;
  v4f var = (T2 - 2.f*m*T1 + m*m*rrsum)*inv + 1e-4f;
  v4f iv;
  float ctp = 0.f, prp = 1.f;
  #pragma unroll
  for (int k=0;k<4;++k){
    iv[k] = 1.f/(2.f*var[k] + EPSF);
    ctp += bu + __logf(var[k]);
    prp *= var[k];
  }
  // combine the 4 e-quads (lane bits 0-1)
  ctp += __shfl_xor(ctp, 1); ctp += __shfl_xor(ctp, 2);
  prp *= __shfl_xor(prp, 1); prp *= __shfl_xor(prp, 2);

  const size_t mbase = ((size_t)b*NO + o)*ND;
  if (cg == 0){                       // lanes 0..3 each write their e-quad
    *(v4f*)(mean0 + mbase + 4*q) = m;
    *(v4f*)(i2v0  + mbase + 4*q) = iv;
  }
  if (t == 0){
    float cost = ctp * rrsum;
    float x  = 5.0e-4f*(beta_a[o] - cost);   // inv_temp iter0 = 0.01*(1-0.95)
    float aj = 1.f/(1.f + __expf(-x));
    float p1 = sqrtf(6.2831853071795864f*prp + EPSF);
    c0[(size_t)b*NO + o] = aj/(p1 + EPSF);
  }
}

// ---------------- final: reduce e-partials, write output (fp32) -------------
// Same wave-parallel structure as k_mred v2.
__global__ __launch_bounds__(64) void k_final(
    const float* __restrict__ beta_a, const float* __restrict__ beta_u,
    const float* __restrict__ S1p, const float* __restrict__ S2p,
    const float* __restrict__ Wsp, const int CH,
    float* __restrict__ out)
{
  const int bo = blockIdx.x;
  const int b = bo >> 6, o = bo & 63;
  const int t = threadIdx.x;
  const int q = t & 3, cg = t >> 2;

  v4f s1 = {0.f,0.f,0.f,0.f}, s2 = {0.f,0.f,0.f,0.f};
  for (int c = cg; c < CH; c += 16){
    const size_t base = ((((size_t)b*CH)+c)*NO + o)*ND + 4*q;
    s1 += *(const v4f*)(S1p + base);
    s2 += *(const v4f*)(S2p + base);
  }
  #pragma unroll
  for (int off=4; off<64; off<<=1){
    #pragma unroll
    for (int k=0;k<4;++k){
      s1[k] += __shfl_xor(s1[k], off);
      s2[k] += __shfl_xor(s2[k], off);
    }
  }
  float wv = 0.f;
  for (int c = t; c < CH; c += 64)
    wv += Wsp[(((size_t)b*CH)+c)*NO + o];
  #pragma unroll
  for (int off=1; off<64; off<<=1) wv += __shfl_xor(wv, off);

  const float Wsum = wv;
  const float inv = 1.f/(Wsum + EPSF);
  const float bu = beta_u[o];
  v4f m   = s1*inv;
  v4f var = (s2 - 2.f*m*s1 + m*m*Wsum)*inv + 1e-4f;
  float ctp = 0.f, nrm = 0.f;
  #pragma unroll
  for (int k=0;k<4;++k){
    ctp += bu + __logf(var[k]);
    float me = m[k] + EPSF;
    nrm += me*me;
  }
  ctp += __shfl_xor(ctp, 1); ctp += __shfl_xor(ctp, 2);
  nrm += __shfl_xor(nrm, 1); nrm += __shfl_xor(nrm, 2);

  const float cost = ctp * Wsum;
  const float x  = 9.75e-4f*(beta_a[o] - cost);  // inv_temp iter1 = 0.01*(1-0.95^2)
  const float aj = 1.f/(1.f + __expf(-x));
  const float scale = aj/(sqrtf(nrm) + EPSF);
  if (cg == 0){                       // lanes 0..3 each write their e-quad
    *(v4f*)(out + (size_t)bo*ND + 4*q) = scale*m;
  }
}

// ---------------- host ------------------------------------------------------
extern "C" void kernel_launch(void* const* d_in, const int* in_sizes, int n_in,
                              void* d_out, int out_size, void* d_ws, size_t ws_size,
                              hipStream_t stream)
{
  const float* u      = (const float*)d_in[0];
  const float* W      = (const float*)d_in[1];
  const float* beta_a = (const float*)d_in[2];
  const float* beta_u = (const float*)d_in[3];
  const float* bias   = (const float*)d_in[4];
  float* ws  = (float*)d_ws;
  float* out = (float*)d_out;

  const size_t base_f = 2u*NB*NO*ND + NB*NO;                  // 135,168 floats
  auto need = [&](int ch){
    return (base_f + 2u*(size_t)NB*ch*NO*ND + (size_t)NB*ch*NO)*4;
  };
  const bool big = (ws_size >= need(64));     // 512-thr / CH=64 path
  const int CH = big ? 64 : 32;

  float* mean0= ws;
  float* i2v0 = mean0 + (size_t)NB*NO*ND;
  float* c0   = i2v0 + (size_t)NB*NO*ND;
  float* S1p  = c0   + (size_t)NB*NO;
  float* S2p  = S1p  + (size_t)NB*CH*NO*ND;
  float* Wsp  = S2p  + (size_t)NB*CH*NO*ND;

  if (big){
    const int GRID = (NB/16)*CH;   // 256 blocks of 8 waves (proven R0 shape)
    k_heavy<8,false><<<GRID, 512, 0, stream>>>(u, W, bias,
                                               nullptr, nullptr, nullptr,
                                               S1p, S2p, Wsp, CH);
    k_mred<<<NB*NO, 64, 0, stream>>>(beta_a, beta_u, S1p, S2p, Wsp, CH,
                                     mean0, i2v0, c0);
    k_heavy<8,true><<<GRID, 512, 0, stream>>>(u, W, bias,
                                              mean0, i2v0, c0,
                                              S1p, S2p, Wsp, CH);
  } else {
    const int GRID = (NB/8)*CH;    // proven R8 shape
    k_heavy<4,false><<<GRID, 256, 0, stream>>>(u, W, bias,
                                               nullptr, nullptr, nullptr,
                                               S1p, S2p, Wsp, CH);
    k_mred<<<NB*NO, 64, 0, stream>>>(beta_a, beta_u, S1p, S2p, Wsp, CH,
                                     mean0, i2v0, c0);
    k_heavy<4,true><<<GRID, 256, 0, stream>>>(u, W, bias,
                                              mean0, i2v0, c0,
                                              S1p, S2p, Wsp, CH);
  }
  k_final<<<NB*NO, 64, 0, stream>>>(beta_a, beta_u, S1p, S2p, Wsp, CH, out);
}